// Round 5
// baseline (219.052 us; speedup 1.0000x reference)
//
#include <hip/hip_runtime.h>

using u32 = unsigned int;
using u16 = unsigned short;

typedef __attribute__((ext_vector_type(8)))  __bf16 bf16x8;
typedef __attribute__((ext_vector_type(16))) float  f32x16;
typedef __attribute__((ext_vector_type(4)))  float  f32x4;
typedef __attribute__((ext_vector_type(4)))  int    i32x4;

__device__ __forceinline__ u32 f2bf(float f){
  u32 u = __float_as_uint(f);
  return (u + 0x7FFFu + ((u >> 16) & 1u)) >> 16;
}
__device__ __forceinline__ u32 pack2bf(float lo, float hi){
  return f2bf(lo) | (f2bf(hi) << 16);
}
__device__ __forceinline__ float bfu2f(u32 us){ return __uint_as_float(us << 16); }
__device__ __forceinline__ float lrelu(float x){ return x > 0.f ? x : 0.01f * x; }

// ---------- K0: weight [512][256] f32 -> wT [256][512] bf16 (+ init M) ----------
__global__ void k0_wt(const float* __restrict__ w, u16* __restrict__ wT, float* __restrict__ M){
  if (blockIdx.x == 0 && threadIdx.x == 0) M[0] = 0.f;
  int u = blockIdx.x * 256 + threadIdx.x;
  int k = u >> 8, n = u & 255;
  wT[(size_t)n * 512 + k] = (u16)f2bf(w[(size_t)k * 256 + n]);
}

// ---------- K1: out = x@W -> outF (MFMA-frag layout), plus s1/s2/v0/v1/max-w ----------
// outF element (k16, n, h, e) = out[i][n] with i = k16*16 + h*8 + e
__global__ __launch_bounds__(512, 2) void k1_gemm(const float* __restrict__ x,
    const u16* __restrict__ wT, const float* __restrict__ av, u16* __restrict__ outF,
    float* __restrict__ s1, float* __restrict__ s2,
    float* __restrict__ v0, float* __restrict__ v1, float* __restrict__ M){
  __shared__ float tb[8][32][36];
  __shared__ float afl[512];
  __shared__ float sred[2][32][17];
  __shared__ float srw[2][32];
  const int i0 = blockIdx.x * 32;
  const int tid = threadIdx.x;
  const int lane = tid & 63, wv = tid >> 6;
  const int r = lane & 31, h = lane >> 5;
  const float* xp = x + (size_t)(i0 + r) * 512 + h * 8;
  const u16*   bp = wT + (size_t)(wv * 32 + r) * 512 + h * 8;
  f32x16 acc = {};
  for (int s = 0; s < 32; ++s){
    f32x4 a0 = *(const f32x4*)xp;
    f32x4 a1 = *(const f32x4*)(xp + 4);
    i32x4 pk = { (int)pack2bf(a0[0], a0[1]), (int)pack2bf(a0[2], a0[3]),
                 (int)pack2bf(a1[0], a1[1]), (int)pack2bf(a1[2], a1[3]) };
    bf16x8 af = __builtin_bit_cast(bf16x8, pk);
    bf16x8 bf = *(const bf16x8*)bp;
    acc = __builtin_amdgcn_mfma_f32_32x32x16_bf16(af, bf, acc, 0, 0, 0);
    xp += 16; bp += 16;
  }
  #pragma unroll
  for (int re = 0; re < 16; ++re){
    int rr = (re & 3) + 8 * (re >> 2) + 4 * h;
    tb[wv][r][rr] = acc[re];
  }
  afl[tid] = av[tid];
  __syncthreads();
  // outF write (frag layout)
  {
    const int n2 = lane >> 1, ic = (lane & 1) * 16;
    const float* tp = &tb[wv][n2][ic];
    i32x4 w0 = { (int)pack2bf(tp[0],tp[1]),   (int)pack2bf(tp[2],tp[3]),
                 (int)pack2bf(tp[4],tp[5]),   (int)pack2bf(tp[6],tp[7]) };
    i32x4 w1 = { (int)pack2bf(tp[8],tp[9]),   (int)pack2bf(tp[10],tp[11]),
                 (int)pack2bf(tp[12],tp[13]), (int)pack2bf(tp[14],tp[15]) };
    const int n = wv * 32 + n2;
    const int k16 = (i0 + ic) >> 4;
    u16* op = outF + ((size_t)k16 * 256 + n) * 16;
    *(i32x4*)op = w0;        // h=0: i offsets 0..7
    *((i32x4*)op + 1) = w1;  // h=1: i offsets 8..15
  }
  // s-dots from f32 acc
  const int row = tid & 31, g = tid >> 5;
  const int w8 = g >> 1, fh = (g & 1) * 16;
  float a1c = 0.f, a2c = 0.f;
  #pragma unroll
  for (int f = 0; f < 16; ++f){
    float tv = tb[w8][fh + f][row];
    a1c = fmaf(tv, afl[w8 * 32 + fh + f], a1c);
    a2c = fmaf(tv, afl[256 + w8 * 32 + fh + f], a2c);
  }
  sred[0][row][g] = a1c; sred[1][row][g] = a2c;
  __syncthreads();
  if (tid < 64){
    int which = tid >> 5, r2 = tid & 31;
    float s = 0.f;
    #pragma unroll
    for (int g2 = 0; g2 < 16; ++g2) s += sred[which][r2][g2];
    (which ? s2 : s1)[i0 + r2] = s;
    srw[which][r2] = s;
  }
  __syncthreads();
  if (tid < 16){
    int k = (i0 >> 1) + tid;
    float sa = srw[0][2*tid], sb = srw[1][2*tid];
    float sa1 = srw[0][2*tid+1], sb1 = srw[1][2*tid+1];
    v0[k] = lrelu(sa + sb);
    v1[k] = lrelu(sa1 + sb1);
    float wv_ = fmaxf(lrelu(sa + sb1), 0.f);
    #pragma unroll
    for (int off = 8; off; off >>= 1) wv_ = fmaxf(wv_, __shfl_down(wv_, off, 16));
    if (tid == 0) atomicMax((int*)M, __float_as_int(wv_));
  }
}

// ---------- K2b2: p = exp(w - M) -> pbf (bf16), pfbot (f32 of bf16), pftop = 1 ----------
__global__ void k2b2(const float* __restrict__ s1, const float* __restrict__ s2,
    const float* __restrict__ M, u16* __restrict__ pbf,
    float* __restrict__ pftop, float* __restrict__ pfbot){
  int k = blockIdx.x * 512 + threadIdx.x;
  float m = M[0];
  float w = lrelu(s1[2*k] + s2[2*k+1]);
  float p = __expf(w - m);
  u32 pb16 = f2bf(p);
  pbf[k] = (u16)pb16;
  pfbot[k] = bfu2f(pb16);
  pftop[k] = 1.0f;
}

// ---------- K2c: out2F = p-scaled outF (same frag layout) ----------
__global__ void k2c_scale(const u16* __restrict__ outF, const u16* __restrict__ pbf,
                          u16* __restrict__ out2F){
  const int u = blockIdx.x * 256 + threadIdx.x;   // 0..262143, 8 elems each
  const size_t off = (size_t)u * 8;
  const int h = u & 1, k16 = u >> 9;
  const int ibase = (k16 * 16 + h * 8) & 4095;
  i32x4 ov = *(const i32x4*)(outF + off);
  i32x4 pv = *(const i32x4*)(pbf + ibase);
  i32x4 rv;
  #pragma unroll
  for (int q = 0; q < 4; ++q){
    u32 o = (u32)ov[q], p = (u32)pv[q];
    rv[q] = (int)pack2bf(bfu2f(o & 0xFFFFu) * bfu2f(p & 0xFFFFu),
                         bfu2f(o >> 16)     * bfu2f(p >> 16));
  }
  *(i32x4*)(out2F + off) = rv;
}

// ---------- K3: binary GEMM, split-K=2, deep pipeline, B-before-adj issue ----------
// grid 512 (2 blocks/CU): xcd 0-3 -> top (outF), 4-7 -> bottom (out2F).
// Block: 32 rows x 256 feats x K-chunk 4096 (32 phases of 128).
// Phase i: B(i+1) issued FIRST, then adj(i+2); MFMA(i) from LDS+B regs; pack adj(i+1)->LDS.
__global__ __launch_bounds__(512, 4) void k3_main(const int* __restrict__ adj,
    const u16* __restrict__ outF, const u16* __restrict__ out2F,
    const float* __restrict__ pftop, const float* __restrict__ pfbot,
    float* __restrict__ P, float* __restrict__ pd){
  __shared__ u16 Ab[2][4096];            // [buf][k16][h][slot^row][8] bf16, XOR-swizzled
  __shared__ float dred[32][17];
  const int bid = blockIdx.x;
  const int xcd = bid & 7, slot = bid >> 3;
  const bool top = xcd < 4;
  const int idx = (top ? xcd : xcd - 4) * 64 + slot;
  const int tile = (top ? 0 : 128) + (idx >> 1);
  const int c = idx & 1;
  const int i0 = tile * 32;
  const int kbase = c * 4096;
  const int pb = tile * 2 + c;
  const u16* BF = top ? outF : out2F;
  const float* pf = top ? pftop : pfbot;
  const int tid = threadIdx.x, lane = tid & 63, wv = tid >> 6;
  const int r = lane & 31, h = lane >> 5, fb = wv * 32;
  const int srow = tid >> 4, sc = tid & 15;
  const int r8 = r * 8, h8 = h * 8, h256 = h * 256;
  const int* aq0 = adj + (size_t)(i0 + srow) * 8192 + kbase + sc * 8;
  const float* pq0 = pf + sc * 8;
  const u16* bq0 = BF + (size_t)kbase * 256 + (fb + r) * 16 + h8;
  u16* const wp0 = &Ab[0][0] + sc * 256 + ((srow ^ sc) * 8);

  i32x4 aA0, aA1, aB0, aB1;
  f32x4 pA0, pA1, pB0, pB1;
  bf16x8 BA[8], BB[8];
  f32x16 acc = {};
  float d = 0.f;

#define ADJ_ISS(A0_,A1_,P0_,P1_,S_) { \
  const int* ap_ = aq0 + (S_) * 128; \
  A0_ = __builtin_nontemporal_load((const i32x4*)ap_); \
  A1_ = __builtin_nontemporal_load((const i32x4*)(ap_ + 4)); \
  const float* pp_ = pq0 + (S_) * 128; \
  P0_ = *(const f32x4*)pp_; P1_ = *(const f32x4*)(pp_ + 4); }

#define B_ISS(B_,S_) { const u16* bb_ = bq0 + (size_t)(S_) * 32768; \
  _Pragma("unroll") for (int ks = 0; ks < 8; ++ks) \
    B_[ks] = *(const bf16x8*)(bb_ + ks * 4096); \
  asm volatile("" ::: "memory"); }          /* pin: B issued before adj */

#define MFMA8(B_,BUF_) { const u16* rb_ = &Ab[BUF_][0]; \
  _Pragma("unroll") for (int ks = 0; ks < 8; ++ks){ \
    bf16x8 a_ = *(const bf16x8*)(rb_ + ks * 512 + h256 + (r8 ^ (ks * 16 + h8))); \
    acc = __builtin_amdgcn_mfma_f32_32x32x16_bf16(a_, B_[ks], acc, 0, 0, 0); } }

#define PACKW(A0_,A1_,P0_,P1_,BUF_) { \
  d = fmaf((float)A0_[0], P0_[0], d); d = fmaf((float)A0_[1], P0_[1], d); \
  d = fmaf((float)A0_[2], P0_[2], d); d = fmaf((float)A0_[3], P0_[3], d); \
  d = fmaf((float)A1_[0], P1_[0], d); d = fmaf((float)A1_[1], P1_[1], d); \
  d = fmaf((float)A1_[2], P1_[2], d); d = fmaf((float)A1_[3], P1_[3], d); \
  i32x4 w_ = { \
    (int)((u32)(A0_[0] * 0x3F80) | ((u32)(A0_[1] * 0x3F8) << 20)), \
    (int)((u32)(A0_[2] * 0x3F80) | ((u32)(A0_[3] * 0x3F8) << 20)), \
    (int)((u32)(A1_[0] * 0x3F80) | ((u32)(A1_[1] * 0x3F8) << 20)), \
    (int)((u32)(A1_[2] * 0x3F80) | ((u32)(A1_[3] * 0x3F8) << 20)) }; \
  *(i32x4*)(wp0 + (BUF_) * 4096) = w_; }

#define KBAR() { asm volatile("s_waitcnt lgkmcnt(0)" ::: "memory"); \
  __builtin_amdgcn_s_barrier(); asm volatile("" ::: "memory"); }

#define STEP2(S_) { \
    B_ISS(BB, (S_)+1); \
    ADJ_ISS(aA0,aA1,pA0,pA1, (S_)+2); \
    MFMA8(BA, 0); \
    PACKW(aB0,aB1,pB0,pB1, 1); \
    KBAR(); \
    B_ISS(BA, (S_)+2); \
    ADJ_ISS(aB0,aB1,pB0,pB1, (S_)+3); \
    MFMA8(BB, 1); \
    PACKW(aA0,aA1,pA0,pA1, 0); \
    KBAR(); }

  // prologue: adj(0)->A, adj(1)->B, B(0)->BA, pack step0 -> buf0
  ADJ_ISS(aA0, aA1, pA0, pA1, 0);
  ADJ_ISS(aB0, aB1, pB0, pB1, 1);
  B_ISS(BA, 0);
  PACKW(aA0, aA1, pA0, pA1, 0);
  KBAR();
  #pragma unroll 1
  for (int s = 0; s < 28; s += 2) STEP2(s);   // phases 0..27: MFMA 0..27, pack 1..28
  // tail phases 28..31 (guarded issues)
  B_ISS(BB, 29); ADJ_ISS(aA0,aA1,pA0,pA1, 30);
  MFMA8(BA, 0); PACKW(aB0,aB1,pB0,pB1, 1); KBAR();
  B_ISS(BA, 30); ADJ_ISS(aB0,aB1,pB0,pB1, 31);
  MFMA8(BB, 1); PACKW(aA0,aA1,pA0,pA1, 0); KBAR();
  B_ISS(BB, 31);
  MFMA8(BA, 0); PACKW(aB0,aB1,pB0,pB1, 1); KBAR();
  MFMA8(BB, 1);

#undef ADJ_ISS
#undef B_ISS
#undef MFMA8
#undef PACKW
#undef STEP2
#undef KBAR

  // ---- epilogue: denominator reduce + partial store ----
  dred[srow][sc] = d;
  __syncthreads();
  if (tid < 32){
    float s = 0.f;
    #pragma unroll
    for (int q = 0; q < 16; ++q) s += dred[tid][q];
    pd[(size_t)pb * 32 + tid] = s;
  }
  float* Pb = P + (size_t)pb * 8192 + fb + r;
  #pragma unroll
  for (int e = 0; e < 16; ++e){
    int rr = (e & 3) + 8 * (e >> 2) + 4 * h;
    __builtin_nontemporal_store(acc[e], Pb + (size_t)rr * 256);
  }
}

// ---------- K4: combine K-split partials + softmax coeffs + sigmoid ----------
__global__ void k4_final(const float* __restrict__ P, const float* __restrict__ pd,
    const float* __restrict__ v0, const float* __restrict__ v1, float* __restrict__ out){
  const int i = blockIdx.x, n = threadIdx.x;
  const int tile = i >> 5, rloc = i & 31;
  const size_t base = (size_t)tile * 16384 + (size_t)rloc * 256 + n;
  float P0 = __builtin_nontemporal_load(P + base);
  float P1 = __builtin_nontemporal_load(P + base + 8192);
  float d0 = pd[tile * 64 + rloc];
  float d1 = pd[tile * 64 + 32 + rloc];
  float val;
  if (i < 4096){
    float va = v0[i], vb = v1[i];
    float m = fmaxf(va, vb);
    float e0 = __expf(va - m), e1 = __expf(vb - m);
    val = (e0 * P0 + e1 * P1) / (e0 * d0 + e1 * d1);
  } else {
    val = (P0 + P1) / (d0 + d1);
  }
  out[(size_t)i * 256 + n] = 1.0f / (1.0f + __expf(-val));
}

extern "C" void kernel_launch(void* const* d_in, const int* in_sizes, int n_in,
                              void* d_out, int out_size, void* d_ws, size_t ws_size,
                              hipStream_t stream)
{
  const float* x      = (const float*)d_in[0];
  const float* weight = (const float*)d_in[1];
  const float* av     = (const float*)d_in[2];
  const int*   adj    = (const int*)d_in[3];
  float* out = (float*)d_out;
  char* ws = (char*)d_ws;
  float* P     = (float*)(ws + 0);             // 16,777,216 B
  float* pd    = (float*)(ws + 16777216);      //     65,536 B
  u16*   outF  = (u16*)  (ws + 16842752);      //  4,194,304 B
  u16*   out2F = (u16*)  (ws + 21037056);      //  4,194,304 B
  u16*   wT    = (u16*)  (ws + 25231360);      //    262,144 B
  u16*   pbf   = (u16*)  (ws + 25493504);      //      8,192 B
  float* pftop = (float*)(ws + 25501696);      //     16,384 B
  float* pfbot = (float*)(ws + 25518080);      //     16,384 B
  float* s1    = (float*)(ws + 25534464);      //     32,768 B
  float* s2    = (float*)(ws + 25567232);      //     32,768 B
  float* v0    = (float*)(ws + 25600000);      //     16,384 B
  float* v1    = (float*)(ws + 25616384);      //     16,384 B
  float* M     = (float*)(ws + 25632768);      //          4 B

  k0_wt    <<<512, 256, 0, stream>>>(weight, wT, M);
  k1_gemm  <<<256, 512, 0, stream>>>(x, wT, av, outF, s1, s2, v0, v1, M);
  k2b2     <<<8, 512, 0, stream>>>(s1, s2, M, pbf, pftop, pfbot);
  k2c_scale<<<1024, 256, 0, stream>>>(outF, pbf, out2F);
  k3_main  <<<512, 512, 0, stream>>>(adj, outF, out2F, pftop, pfbot, P, pd);
  k4_final <<<8192, 256, 0, stream>>>(P, pd, v0, v1, out);
}

// Round 6
// 137.929 us; speedup vs baseline: 1.5881x; 1.5881x over previous
//
#include <hip/hip_runtime.h>

using u32 = unsigned int;
using u16 = unsigned short;

typedef __attribute__((ext_vector_type(8)))  __bf16 bf16x8;
typedef __attribute__((ext_vector_type(16))) float  f32x16;
typedef __attribute__((ext_vector_type(4)))  float  f32x4;
typedef __attribute__((ext_vector_type(4)))  int    i32x4;

__device__ __forceinline__ u32 f2bf(float f){
  u32 u = __float_as_uint(f);
  return (u + 0x7FFFu + ((u >> 16) & 1u)) >> 16;
}
__device__ __forceinline__ u32 pack2bf(float lo, float hi){
  return f2bf(lo) | (f2bf(hi) << 16);
}
__device__ __forceinline__ float bfu2f(u32 us){ return __uint_as_float(us << 16); }
__device__ __forceinline__ float lrelu(float x){ return x > 0.f ? x : 0.01f * x; }

// ---------- K0: weight [512][256] f32 -> wT [256][512] bf16 (+ init M) ----------
__global__ void k0_wt(const float* __restrict__ w, u16* __restrict__ wT, float* __restrict__ M){
  if (blockIdx.x == 0 && threadIdx.x == 0) M[0] = 0.f;
  int u = blockIdx.x * 256 + threadIdx.x;
  int k = u >> 8, n = u & 255;
  wT[(size_t)n * 512 + k] = (u16)f2bf(w[(size_t)k * 256 + n]);
}

// ---------- K1: out = x@W -> outF (MFMA-frag layout), plus s1/s2/v0/v1/max-w ----------
// outF element (k16, n, h, e) = out[i][n] with i = k16*16 + h*8 + e
__global__ __launch_bounds__(512, 2) void k1_gemm(const float* __restrict__ x,
    const u16* __restrict__ wT, const float* __restrict__ av, u16* __restrict__ outF,
    float* __restrict__ s1, float* __restrict__ s2,
    float* __restrict__ v0, float* __restrict__ v1, float* __restrict__ M){
  __shared__ float tb[8][32][36];
  __shared__ float afl[512];
  __shared__ float sred[2][32][17];
  __shared__ float srw[2][32];
  const int i0 = blockIdx.x * 32;
  const int tid = threadIdx.x;
  const int lane = tid & 63, wv = tid >> 6;
  const int r = lane & 31, h = lane >> 5;
  const float* xp = x + (size_t)(i0 + r) * 512 + h * 8;
  const u16*   bp = wT + (size_t)(wv * 32 + r) * 512 + h * 8;
  f32x16 acc = {};
  for (int s = 0; s < 32; ++s){
    f32x4 a0 = *(const f32x4*)xp;
    f32x4 a1 = *(const f32x4*)(xp + 4);
    i32x4 pk = { (int)pack2bf(a0[0], a0[1]), (int)pack2bf(a0[2], a0[3]),
                 (int)pack2bf(a1[0], a1[1]), (int)pack2bf(a1[2], a1[3]) };
    bf16x8 af = __builtin_bit_cast(bf16x8, pk);
    bf16x8 bf = *(const bf16x8*)bp;
    acc = __builtin_amdgcn_mfma_f32_32x32x16_bf16(af, bf, acc, 0, 0, 0);
    xp += 16; bp += 16;
  }
  #pragma unroll
  for (int re = 0; re < 16; ++re){
    int rr = (re & 3) + 8 * (re >> 2) + 4 * h;
    tb[wv][r][rr] = acc[re];
  }
  afl[tid] = av[tid];
  __syncthreads();
  // outF write (frag layout)
  {
    const int n2 = lane >> 1, ic = (lane & 1) * 16;
    const float* tp = &tb[wv][n2][ic];
    i32x4 w0 = { (int)pack2bf(tp[0],tp[1]),   (int)pack2bf(tp[2],tp[3]),
                 (int)pack2bf(tp[4],tp[5]),   (int)pack2bf(tp[6],tp[7]) };
    i32x4 w1 = { (int)pack2bf(tp[8],tp[9]),   (int)pack2bf(tp[10],tp[11]),
                 (int)pack2bf(tp[12],tp[13]), (int)pack2bf(tp[14],tp[15]) };
    const int n = wv * 32 + n2;
    const int k16 = (i0 + ic) >> 4;
    u16* op = outF + ((size_t)k16 * 256 + n) * 16;
    *(i32x4*)op = w0;        // h=0: i offsets 0..7
    *((i32x4*)op + 1) = w1;  // h=1: i offsets 8..15
  }
  // s-dots from f32 acc
  const int row = tid & 31, g = tid >> 5;
  const int w8 = g >> 1, fh = (g & 1) * 16;
  float a1c = 0.f, a2c = 0.f;
  #pragma unroll
  for (int f = 0; f < 16; ++f){
    float tv = tb[w8][fh + f][row];
    a1c = fmaf(tv, afl[w8 * 32 + fh + f], a1c);
    a2c = fmaf(tv, afl[256 + w8 * 32 + fh + f], a2c);
  }
  sred[0][row][g] = a1c; sred[1][row][g] = a2c;
  __syncthreads();
  if (tid < 64){
    int which = tid >> 5, r2 = tid & 31;
    float s = 0.f;
    #pragma unroll
    for (int g2 = 0; g2 < 16; ++g2) s += sred[which][r2][g2];
    (which ? s2 : s1)[i0 + r2] = s;
    srw[which][r2] = s;
  }
  __syncthreads();
  if (tid < 16){
    int k = (i0 >> 1) + tid;
    float sa = srw[0][2*tid], sb = srw[1][2*tid];
    float sa1 = srw[0][2*tid+1], sb1 = srw[1][2*tid+1];
    v0[k] = lrelu(sa + sb);
    v1[k] = lrelu(sa1 + sb1);
    float wv_ = fmaxf(lrelu(sa + sb1), 0.f);
    #pragma unroll
    for (int off = 8; off; off >>= 1) wv_ = fmaxf(wv_, __shfl_down(wv_, off, 16));
    if (tid == 0) atomicMax((int*)M, __float_as_int(wv_));
  }
}

// ---------- K2b2: p = exp(w - M) -> pbf (bf16), pfbot (f32 of bf16) ----------
__global__ void k2b2(const float* __restrict__ s1, const float* __restrict__ s2,
    const float* __restrict__ M, u16* __restrict__ pbf, float* __restrict__ pfbot){
  int k = blockIdx.x * 512 + threadIdx.x;
  float m = M[0];
  float w = lrelu(s1[2*k] + s2[2*k+1]);
  float p = __expf(w - m);
  u32 pb16 = f2bf(p);
  pbf[k] = (u16)pb16;
  pfbot[k] = bfu2f(pb16);
}

// ---------- K2c: out2F = p-scaled outF (same frag layout) ----------
__global__ void k2c_scale(const u16* __restrict__ outF, const u16* __restrict__ pbf,
                          u16* __restrict__ out2F){
  const int u = blockIdx.x * 256 + threadIdx.x;   // 0..262143, 8 elems each
  const size_t off = (size_t)u * 8;
  const int h = u & 1, k16 = u >> 9;
  const int ibase = (k16 * 16 + h * 8) & 4095;
  i32x4 ov = *(const i32x4*)(outF + off);
  i32x4 pv = *(const i32x4*)(pbf + ibase);
  i32x4 rv;
  #pragma unroll
  for (int q = 0; q < 4; ++q){
    u32 o = (u32)ov[q], p = (u32)pv[q];
    rv[q] = (int)pack2bf(bfu2f(o & 0xFFFFu) * bfu2f(p & 0xFFFFu),
                         bfu2f(o >> 16)     * bfu2f(p >> 16));
  }
  *(i32x4*)(out2F + off) = rv;
}

// ---------- K3: binary GEMM, split-K=2, deep pipeline, lean registers ----------
// grid 512 (2 blocks/CU): xcd 0-3 -> top (outF), 4-7 -> bottom (out2F).
// Block: 32 rows x 256 feats x K-chunk 4096 (32 phases of 128).
// Phase i: issue B(i+1) FIRST; MFMA(i) from LDS+B regs; PACKW consumes adj(i+1)
// (p read from LDS); then re-issue adj(i+2) into the SAME regs. One vmcnt wait
// per consumer, loads always ≥1 full phase in flight.
__global__ __launch_bounds__(512, 2) void k3_main(const int* __restrict__ adj,
    const u16* __restrict__ outF, const u16* __restrict__ out2F,
    const float* __restrict__ pfbot,
    float* __restrict__ P, float* __restrict__ pd){
  __shared__ u16 Ab[2][4096];            // [buf][k16][h][slot^row][8] bf16, XOR-swizzled
  __shared__ float pl[4096];             // p vector for this K-chunk (f32)
  __shared__ float dred[32][17];
  const int bid = blockIdx.x;
  const int xcd = bid & 7, slot = bid >> 3;
  const bool top = xcd < 4;
  const int idx = (top ? xcd : xcd - 4) * 64 + slot;
  const int tile = (top ? 0 : 128) + (idx >> 1);
  const int c = idx & 1;
  const int i0 = tile * 32;
  const int kbase = c * 4096;
  const int pb = tile * 2 + c;
  const u16* BF = top ? outF : out2F;
  const int tid = threadIdx.x, lane = tid & 63, wv = tid >> 6;
  const int r = lane & 31, h = lane >> 5, fb = wv * 32;
  const int srow = tid >> 4, sc = tid & 15;
  const int r8 = r * 8, h8 = h * 8, h256 = h * 256;
  const int* aq0 = adj + (size_t)(i0 + srow) * 8192 + kbase + sc * 8;
  const u16* bq0 = BF + (size_t)kbase * 256 + (fb + r) * 16 + h8;
  u16* const wp0 = &Ab[0][0] + sc * 256 + ((srow ^ sc) * 8);
  const float* const pq0 = pl + sc * 8;

  // stage p into LDS (p has period 4096, so chunk-independent)
  {
    const int j = tid * 8;
    if (top){
      f32x4 one = {1.f, 1.f, 1.f, 1.f};
      *(f32x4*)(pl + j) = one; *(f32x4*)(pl + j + 4) = one;
    } else {
      *(f32x4*)(pl + j)     = *(const f32x4*)(pfbot + j);
      *(f32x4*)(pl + j + 4) = *(const f32x4*)(pfbot + j + 4);
    }
  }
  __syncthreads();

  i32x4 ar0, ar1;
  bf16x8 BA[8], BB[8];
  f32x16 acc = {};
  float d = 0.f;

#define ADJ_ISS(S_) { \
  const int* ap_ = aq0 + (S_) * 128; \
  ar0 = __builtin_nontemporal_load((const i32x4*)ap_); \
  ar1 = __builtin_nontemporal_load((const i32x4*)(ap_ + 4)); }

#define B_ISS(B_,S_) { const u16* bb_ = bq0 + (size_t)(S_) * 32768; \
  _Pragma("unroll") for (int ks = 0; ks < 8; ++ks) \
    B_[ks] = *(const bf16x8*)(bb_ + ks * 4096); \
  asm volatile("" ::: "memory"); }

#define MFMA8(B_,BUF_) { const u16* rb_ = &Ab[BUF_][0]; \
  _Pragma("unroll") for (int ks = 0; ks < 8; ++ks){ \
    bf16x8 a_ = *(const bf16x8*)(rb_ + ks * 512 + h256 + (r8 ^ (ks * 16 + h8))); \
    acc = __builtin_amdgcn_mfma_f32_32x32x16_bf16(a_, B_[ks], acc, 0, 0, 0); } }

#define PACKW(BUF_,S_) { \
  const float* pp_ = pq0 + (S_) * 128; \
  f32x4 p0_ = *(const f32x4*)pp_; f32x4 p1_ = *(const f32x4*)(pp_ + 4); \
  d = fmaf((float)ar0[0], p0_[0], d); d = fmaf((float)ar0[1], p0_[1], d); \
  d = fmaf((float)ar0[2], p0_[2], d); d = fmaf((float)ar0[3], p0_[3], d); \
  d = fmaf((float)ar1[0], p1_[0], d); d = fmaf((float)ar1[1], p1_[1], d); \
  d = fmaf((float)ar1[2], p1_[2], d); d = fmaf((float)ar1[3], p1_[3], d); \
  i32x4 w_ = { \
    (int)((u32)(ar0[0] * 0x3F80) | ((u32)(ar0[1] * 0x3F8) << 20)), \
    (int)((u32)(ar0[2] * 0x3F80) | ((u32)(ar0[3] * 0x3F8) << 20)), \
    (int)((u32)(ar1[0] * 0x3F80) | ((u32)(ar1[1] * 0x3F8) << 20)), \
    (int)((u32)(ar1[2] * 0x3F80) | ((u32)(ar1[3] * 0x3F8) << 20)) }; \
  *(i32x4*)(wp0 + (BUF_) * 4096) = w_; }

#define KBAR() { asm volatile("s_waitcnt lgkmcnt(0)" ::: "memory"); \
  __builtin_amdgcn_s_barrier(); asm volatile("" ::: "memory"); }

  // prologue: adj(0) -> pack buf0; issue adj(1), B(0)
  ADJ_ISS(0);
  B_ISS(BA, 0);
  PACKW(0, 0);
  ADJ_ISS(1);
  KBAR();
  #pragma unroll 1
  for (int s = 0; s < 28; s += 2){
    B_ISS(BB, s + 1);  MFMA8(BA, 0);  PACKW(1, s + 1);  ADJ_ISS(s + 2);  KBAR();
    B_ISS(BA, s + 2);  MFMA8(BB, 1);  PACKW(0, s + 2);  ADJ_ISS(s + 3);  KBAR();
  }
  // tail phases 28..31
  B_ISS(BB, 29);  MFMA8(BA, 0);  PACKW(1, 29);  ADJ_ISS(30);  KBAR();
  B_ISS(BA, 30);  MFMA8(BB, 1);  PACKW(0, 30);  ADJ_ISS(31);  KBAR();
  B_ISS(BB, 31);  MFMA8(BA, 0);  PACKW(1, 31);  KBAR();
  MFMA8(BB, 1);

#undef ADJ_ISS
#undef B_ISS
#undef MFMA8
#undef PACKW
#undef KBAR

  // ---- epilogue: denominator reduce + partial store ----
  dred[srow][sc] = d;
  __syncthreads();
  if (tid < 32){
    float s = 0.f;
    #pragma unroll
    for (int q = 0; q < 16; ++q) s += dred[tid][q];
    pd[(size_t)pb * 32 + tid] = s;
  }
  float* Pb = P + (size_t)pb * 8192 + fb + r;
  #pragma unroll
  for (int e = 0; e < 16; ++e){
    int rr = (e & 3) + 8 * (e >> 2) + 4 * h;
    __builtin_nontemporal_store(acc[e], Pb + (size_t)rr * 256);
  }
}

// ---------- K4: combine K-split partials + softmax coeffs + sigmoid ----------
__global__ void k4_final(const float* __restrict__ P, const float* __restrict__ pd,
    const float* __restrict__ v0, const float* __restrict__ v1, float* __restrict__ out){
  const int i = blockIdx.x, n = threadIdx.x;
  const int tile = i >> 5, rloc = i & 31;
  const size_t base = (size_t)tile * 16384 + (size_t)rloc * 256 + n;
  float P0 = __builtin_nontemporal_load(P + base);
  float P1 = __builtin_nontemporal_load(P + base + 8192);
  float d0 = pd[tile * 64 + rloc];
  float d1 = pd[tile * 64 + 32 + rloc];
  float val;
  if (i < 4096){
    float va = v0[i], vb = v1[i];
    float m = fmaxf(va, vb);
    float e0 = __expf(va - m), e1 = __expf(vb - m);
    val = (e0 * P0 + e1 * P1) / (e0 * d0 + e1 * d1);
  } else {
    val = (P0 + P1) / (d0 + d1);
  }
  out[(size_t)i * 256 + n] = 1.0f / (1.0f + __expf(-val));
}

extern "C" void kernel_launch(void* const* d_in, const int* in_sizes, int n_in,
                              void* d_out, int out_size, void* d_ws, size_t ws_size,
                              hipStream_t stream)
{
  const float* x      = (const float*)d_in[0];
  const float* weight = (const float*)d_in[1];
  const float* av     = (const float*)d_in[2];
  const int*   adj    = (const int*)d_in[3];
  float* out = (float*)d_out;
  char* ws = (char*)d_ws;
  float* P     = (float*)(ws + 0);             // 16,777,216 B
  float* pd    = (float*)(ws + 16777216);      //     65,536 B
  u16*   outF  = (u16*)  (ws + 16842752);      //  4,194,304 B
  u16*   out2F = (u16*)  (ws + 21037056);      //  4,194,304 B
  u16*   wT    = (u16*)  (ws + 25231360);      //    262,144 B
  u16*   pbf   = (u16*)  (ws + 25493504);      //      8,192 B
  float* pfbot = (float*)(ws + 25501696);      //     16,384 B
  float* s1    = (float*)(ws + 25518080);      //     32,768 B
  float* s2    = (float*)(ws + 25550848);      //     32,768 B
  float* v0    = (float*)(ws + 25583616);      //     16,384 B
  float* v1    = (float*)(ws + 25600000);      //     16,384 B
  float* M     = (float*)(ws + 25616384);      //          4 B

  k0_wt    <<<512, 256, 0, stream>>>(weight, wT, M);
  k1_gemm  <<<256, 512, 0, stream>>>(x, wT, av, outF, s1, s2, v0, v1, M);
  k2b2     <<<8, 512, 0, stream>>>(s1, s2, M, pbf, pfbot);
  k2c_scale<<<1024, 256, 0, stream>>>(outF, pbf, out2F);
  k3_main  <<<512, 512, 0, stream>>>(adj, outF, out2F, pfbot, P, pd);
  k4_final <<<8192, 256, 0, stream>>>(P, pd, v0, v1, out);
}

// Round 7
// 135.814 us; speedup vs baseline: 1.6129x; 1.0156x over previous
//
#include <hip/hip_runtime.h>

using u32 = unsigned int;
using u16 = unsigned short;

typedef __attribute__((ext_vector_type(8)))  __bf16 bf16x8;
typedef __attribute__((ext_vector_type(16))) float  f32x16;
typedef __attribute__((ext_vector_type(4)))  float  f32x4;
typedef __attribute__((ext_vector_type(4)))  int    i32x4;

__device__ __forceinline__ u32 f2bf(float f){
  u32 u = __float_as_uint(f);
  return (u + 0x7FFFu + ((u >> 16) & 1u)) >> 16;
}
__device__ __forceinline__ u32 pack2bf(float lo, float hi){
  return f2bf(lo) | (f2bf(hi) << 16);
}
__device__ __forceinline__ float bfu2f(u32 us){ return __uint_as_float(us << 16); }
__device__ __forceinline__ float lrelu(float x){ return x > 0.f ? x : 0.01f * x; }

// ---------- K0: weight [512][256] f32 -> wT [256][512] bf16 ----------
__global__ void k0_wt(const float* __restrict__ w, u16* __restrict__ wT){
  int u = blockIdx.x * 256 + threadIdx.x;
  int k = u >> 8, n = u & 255;
  wT[(size_t)n * 512 + k] = (u16)f2bf(w[(size_t)k * 256 + n]);
}

// ---------- K1: out = x@W -> outF (MFMA-frag layout) + s-dots + v0/v1 + p ----------
// outF element (k16, n, h, e) = out[i][n] with i = k16*16 + h*8 + e
// p computed with shift C=0 (softmax shift-invariant; w <= ~6 sigma, exp safe).
__global__ __launch_bounds__(512, 2) void k1_gemm(const float* __restrict__ x,
    const u16* __restrict__ wT, const float* __restrict__ av, u16* __restrict__ outF,
    float* __restrict__ v0, float* __restrict__ v1,
    u16* __restrict__ pbf, float* __restrict__ pfbot){
  __shared__ float tb[8][32][36];
  __shared__ float afl[512];
  __shared__ float sred[2][32][17];
  __shared__ float srw[2][32];
  const int i0 = blockIdx.x * 32;
  const int tid = threadIdx.x;
  const int lane = tid & 63, wv = tid >> 6;
  const int r = lane & 31, h = lane >> 5;
  const float* xp = x + (size_t)(i0 + r) * 512 + h * 8;
  const u16*   bp = wT + (size_t)(wv * 32 + r) * 512 + h * 8;
  f32x16 acc = {};
  for (int s = 0; s < 32; ++s){
    f32x4 a0 = *(const f32x4*)xp;
    f32x4 a1 = *(const f32x4*)(xp + 4);
    i32x4 pk = { (int)pack2bf(a0[0], a0[1]), (int)pack2bf(a0[2], a0[3]),
                 (int)pack2bf(a1[0], a1[1]), (int)pack2bf(a1[2], a1[3]) };
    bf16x8 af = __builtin_bit_cast(bf16x8, pk);
    bf16x8 bf = *(const bf16x8*)bp;
    acc = __builtin_amdgcn_mfma_f32_32x32x16_bf16(af, bf, acc, 0, 0, 0);
    xp += 16; bp += 16;
  }
  #pragma unroll
  for (int re = 0; re < 16; ++re){
    int rr = (re & 3) + 8 * (re >> 2) + 4 * h;
    tb[wv][r][rr] = acc[re];
  }
  afl[tid] = av[tid];
  __syncthreads();
  // outF write (frag layout)
  {
    const int n2 = lane >> 1, ic = (lane & 1) * 16;
    const float* tp = &tb[wv][n2][ic];
    i32x4 w0 = { (int)pack2bf(tp[0],tp[1]),   (int)pack2bf(tp[2],tp[3]),
                 (int)pack2bf(tp[4],tp[5]),   (int)pack2bf(tp[6],tp[7]) };
    i32x4 w1 = { (int)pack2bf(tp[8],tp[9]),   (int)pack2bf(tp[10],tp[11]),
                 (int)pack2bf(tp[12],tp[13]), (int)pack2bf(tp[14],tp[15]) };
    const int n = wv * 32 + n2;
    const int k16 = (i0 + ic) >> 4;
    u16* op = outF + ((size_t)k16 * 256 + n) * 16;
    *(i32x4*)op = w0;
    *((i32x4*)op + 1) = w1;
  }
  // s-dots from f32 acc
  const int row = tid & 31, g = tid >> 5;
  const int w8 = g >> 1, fh = (g & 1) * 16;
  float a1c = 0.f, a2c = 0.f;
  #pragma unroll
  for (int f = 0; f < 16; ++f){
    float tv = tb[w8][fh + f][row];
    a1c = fmaf(tv, afl[w8 * 32 + fh + f], a1c);
    a2c = fmaf(tv, afl[256 + w8 * 32 + fh + f], a2c);
  }
  sred[0][row][g] = a1c; sred[1][row][g] = a2c;
  __syncthreads();
  if (tid < 64){
    int which = tid >> 5, r2 = tid & 31;
    float s = 0.f;
    #pragma unroll
    for (int g2 = 0; g2 < 16; ++g2) s += sred[which][r2][g2];
    srw[which][r2] = s;
  }
  __syncthreads();
  if (tid < 16){
    int k = (i0 >> 1) + tid;
    float sa  = srw[0][2*tid],   sb  = srw[1][2*tid];
    float sa1 = srw[0][2*tid+1], sb1 = srw[1][2*tid+1];
    v0[k] = lrelu(sa + sb);
    v1[k] = lrelu(sa1 + sb1);
    float w = lrelu(sa + sb1);
    u32 pb = f2bf(__expf(w));
    pbf[k] = (u16)pb;
    pfbot[k] = bfu2f(pb);
  }
}

// ---------- K2c: out2F = p-scaled outF (same frag layout) ----------
__global__ void k2c_scale(const u16* __restrict__ outF, const u16* __restrict__ pbf,
                          u16* __restrict__ out2F){
  const int u = blockIdx.x * 256 + threadIdx.x;   // 0..262143, 8 elems each
  const size_t off = (size_t)u * 8;
  const int h = u & 1, k16 = u >> 9;
  const int ibase = (k16 * 16 + h * 8) & 4095;
  i32x4 ov = *(const i32x4*)(outF + off);
  i32x4 pv = *(const i32x4*)(pbf + ibase);
  i32x4 rv;
  #pragma unroll
  for (int q = 0; q < 4; ++q){
    u32 o = (u32)ov[q], p = (u32)pv[q];
    rv[q] = (int)pack2bf(bfu2f(o & 0xFFFFu) * bfu2f(p & 0xFFFFu),
                         bfu2f(o >> 16)     * bfu2f(p >> 16));
  }
  *(i32x4*)(out2F + off) = rv;
}

// ---------- K3: binary GEMM, split-K=2, deep pipeline, 2 adj reg sets ----------
// grid 512 (2 blocks/CU): xcd 0-3 -> top (outF), 4-7 -> bottom (out2F).
// Block: 32 rows x 256 feats x K-chunk 4096 (32 phases of 128).
// Phase: B_ISS(s+1); ADJ_ISS(s+2) [alternate reg set]; MFMA(s); PACKW(s+1); bar.
// adj slack ~1.4 phases; B slack ~1 phase; loads stay in flight across barriers.
__global__ __launch_bounds__(512, 2) void k3_main(const int* __restrict__ adj,
    const u16* __restrict__ outF, const u16* __restrict__ out2F,
    const float* __restrict__ pfbot,
    float* __restrict__ P, float* __restrict__ pd){
  __shared__ u16 Ab[2][4096];            // [buf][k16][h][slot^row][8] bf16, XOR-swizzled
  __shared__ float pl[4096];             // p vector (f32), period-4096
  __shared__ float dred[32][17];
  const int bid = blockIdx.x;
  const int xcd = bid & 7, slot = bid >> 3;
  const bool top = xcd < 4;
  const int idx = (top ? xcd : xcd - 4) * 64 + slot;
  const int tile = (top ? 0 : 128) + (idx >> 1);
  const int c = idx & 1;
  const int i0 = tile * 32;
  const int kbase = c * 4096;
  const int pb = tile * 2 + c;
  const u16* BF = top ? outF : out2F;
  const int tid = threadIdx.x, lane = tid & 63, wv = tid >> 6;
  const int r = lane & 31, h = lane >> 5, fb = wv * 32;
  const int srow = tid >> 4, sc = tid & 15;
  const int r8 = r * 8, h8 = h * 8, h256 = h * 256;
  const int* aq0 = adj + (size_t)(i0 + srow) * 8192 + kbase + sc * 8;
  const u16* bq0 = BF + (size_t)kbase * 256 + (fb + r) * 16 + h8;
  u16* const wp0 = &Ab[0][0] + sc * 256 + ((srow ^ sc) * 8);
  const float* const pq0 = pl + sc * 8;

  // stage p into LDS (chunk-independent: p has period 4096)
  {
    const int j = tid * 8;
    if (top){
      f32x4 one = {1.f, 1.f, 1.f, 1.f};
      *(f32x4*)(pl + j) = one; *(f32x4*)(pl + j + 4) = one;
    } else {
      *(f32x4*)(pl + j)     = *(const f32x4*)(pfbot + j);
      *(f32x4*)(pl + j + 4) = *(const f32x4*)(pfbot + j + 4);
    }
  }
  __syncthreads();

  i32x4 aA0, aA1, aB0, aB1;
  bf16x8 BA[8], BB[8];
  f32x16 acc = {};
  float d = 0.f;

#define ADJ_A(S_) { const int* ap_ = aq0 + (S_) * 128; \
  aA0 = __builtin_nontemporal_load((const i32x4*)ap_); \
  aA1 = __builtin_nontemporal_load((const i32x4*)(ap_ + 4)); \
  asm volatile("" ::: "memory"); }
#define ADJ_B(S_) { const int* ap_ = aq0 + (S_) * 128; \
  aB0 = __builtin_nontemporal_load((const i32x4*)ap_); \
  aB1 = __builtin_nontemporal_load((const i32x4*)(ap_ + 4)); \
  asm volatile("" ::: "memory"); }

#define B_ISS(B_,S_) { const u16* bb_ = bq0 + (size_t)(S_) * 32768; \
  _Pragma("unroll") for (int ks = 0; ks < 8; ++ks) \
    B_[ks] = *(const bf16x8*)(bb_ + ks * 4096); \
  asm volatile("" ::: "memory"); }

#define MFMA8(B_,BUF_) { const u16* rb_ = &Ab[BUF_][0]; \
  __builtin_amdgcn_s_setprio(1); \
  _Pragma("unroll") for (int ks = 0; ks < 8; ++ks){ \
    bf16x8 a_ = *(const bf16x8*)(rb_ + ks * 512 + h256 + (r8 ^ (ks * 16 + h8))); \
    acc = __builtin_amdgcn_mfma_f32_32x32x16_bf16(a_, B_[ks], acc, 0, 0, 0); } \
  __builtin_amdgcn_s_setprio(0); }

#define PACKW(A0_,A1_,BUF_,S_) { \
  const float* pp_ = pq0 + (S_) * 128; \
  f32x4 p0_ = *(const f32x4*)pp_; f32x4 p1_ = *(const f32x4*)(pp_ + 4); \
  d = fmaf((float)A0_[0], p0_[0], d); d = fmaf((float)A0_[1], p0_[1], d); \
  d = fmaf((float)A0_[2], p0_[2], d); d = fmaf((float)A0_[3], p0_[3], d); \
  d = fmaf((float)A1_[0], p1_[0], d); d = fmaf((float)A1_[1], p1_[1], d); \
  d = fmaf((float)A1_[2], p1_[2], d); d = fmaf((float)A1_[3], p1_[3], d); \
  i32x4 w_ = { \
    (int)((u32)(A0_[0] * 0x3F80) | ((u32)(A0_[1] * 0x3F8) << 20)), \
    (int)((u32)(A0_[2] * 0x3F80) | ((u32)(A0_[3] * 0x3F8) << 20)), \
    (int)((u32)(A1_[0] * 0x3F80) | ((u32)(A1_[1] * 0x3F8) << 20)), \
    (int)((u32)(A1_[2] * 0x3F80) | ((u32)(A1_[3] * 0x3F8) << 20)) }; \
  *(i32x4*)(wp0 + (BUF_) * 4096) = w_; }

#define KBAR() { asm volatile("s_waitcnt lgkmcnt(0)" ::: "memory"); \
  __builtin_amdgcn_s_barrier(); asm volatile("" ::: "memory"); }

  // prologue: adj(0)->A (consumed now), B(0)->BA, adj(1)->B
  ADJ_A(0);
  B_ISS(BA, 0);
  ADJ_B(1);
  PACKW(aA0, aA1, 0, 0);
  KBAR();
  #pragma unroll 1
  for (int s = 0; s < 28; s += 2){
    B_ISS(BB, s + 1);  ADJ_A(s + 2);  MFMA8(BA, 0);  PACKW(aB0, aB1, 1, s + 1);  KBAR();
    B_ISS(BA, s + 2);  ADJ_B(s + 3);  MFMA8(BB, 1);  PACKW(aA0, aA1, 0, s + 2);  KBAR();
  }
  // tail: steps 28..31
  B_ISS(BB, 29);  ADJ_A(30);  MFMA8(BA, 0);  PACKW(aB0, aB1, 1, 29);  KBAR();
  B_ISS(BA, 30);  ADJ_B(31);  MFMA8(BB, 1);  PACKW(aA0, aA1, 0, 30);  KBAR();
  B_ISS(BB, 31);              MFMA8(BA, 0);  PACKW(aB0, aB1, 1, 31);  KBAR();
  MFMA8(BB, 1);

#undef ADJ_A
#undef ADJ_B
#undef B_ISS
#undef MFMA8
#undef PACKW
#undef KBAR

  // ---- epilogue: denominator reduce + partial store ----
  dred[srow][sc] = d;
  __syncthreads();
  if (tid < 32){
    float s = 0.f;
    #pragma unroll
    for (int q = 0; q < 16; ++q) s += dred[tid][q];
    pd[(size_t)pb * 32 + tid] = s;
  }
  float* Pb = P + (size_t)pb * 8192 + fb + r;
  #pragma unroll
  for (int e = 0; e < 16; ++e){
    int rr = (e & 3) + 8 * (e >> 2) + 4 * h;
    __builtin_nontemporal_store(acc[e], Pb + (size_t)rr * 256);
  }
}

// ---------- K4: combine K-split partials + softmax coeffs + sigmoid ----------
__global__ void k4_final(const float* __restrict__ P, const float* __restrict__ pd,
    const float* __restrict__ v0, const float* __restrict__ v1, float* __restrict__ out){
  const int i = blockIdx.x, n = threadIdx.x;
  const int tile = i >> 5, rloc = i & 31;
  const size_t base = (size_t)tile * 16384 + (size_t)rloc * 256 + n;
  float P0 = __builtin_nontemporal_load(P + base);
  float P1 = __builtin_nontemporal_load(P + base + 8192);
  float d0 = pd[tile * 64 + rloc];
  float d1 = pd[tile * 64 + 32 + rloc];
  float val;
  if (i < 4096){
    float va = v0[i], vb = v1[i];
    float m = fmaxf(va, vb);
    float e0 = __expf(va - m), e1 = __expf(vb - m);
    val = (e0 * P0 + e1 * P1) / (e0 * d0 + e1 * d1);
  } else {
    val = (P0 + P1) / (d0 + d1);
  }
  out[(size_t)i * 256 + n] = 1.0f / (1.0f + __expf(-val));
}

extern "C" void kernel_launch(void* const* d_in, const int* in_sizes, int n_in,
                              void* d_out, int out_size, void* d_ws, size_t ws_size,
                              hipStream_t stream)
{
  const float* x      = (const float*)d_in[0];
  const float* weight = (const float*)d_in[1];
  const float* av     = (const float*)d_in[2];
  const int*   adj    = (const int*)d_in[3];
  float* out = (float*)d_out;
  char* ws = (char*)d_ws;
  float* P     = (float*)(ws + 0);             // 16,777,216 B
  float* pd    = (float*)(ws + 16777216);      //     65,536 B
  u16*   outF  = (u16*)  (ws + 16842752);      //  4,194,304 B
  u16*   out2F = (u16*)  (ws + 21037056);      //  4,194,304 B
  u16*   wT    = (u16*)  (ws + 25231360);      //    262,144 B
  u16*   pbf   = (u16*)  (ws + 25493504);      //      8,192 B
  float* pfbot = (float*)(ws + 25501696);      //     16,384 B
  float* v0    = (float*)(ws + 25518080);      //     16,384 B
  float* v1    = (float*)(ws + 25534464);      //     16,384 B

  k0_wt    <<<512, 256, 0, stream>>>(weight, wT);
  k1_gemm  <<<256, 512, 0, stream>>>(x, wT, av, outF, v0, v1, pbf, pfbot);
  k2c_scale<<<1024, 256, 0, stream>>>(outF, pbf, out2F);
  k3_main  <<<512, 512, 0, stream>>>(adj, outF, out2F, pfbot, P, pd);
  k4_final <<<8192, 256, 0, stream>>>(P, pd, v0, v1, out);
}

// Round 8
// 129.400 us; speedup vs baseline: 1.6928x; 1.0496x over previous
//
#include <hip/hip_runtime.h>

using u32 = unsigned int;
using u16 = unsigned short;

typedef __attribute__((ext_vector_type(8)))  __bf16 bf16x8;
typedef __attribute__((ext_vector_type(16))) float  f32x16;
typedef __attribute__((ext_vector_type(4)))  float  f32x4;
typedef __attribute__((ext_vector_type(4)))  int    i32x4;

__device__ __forceinline__ u32 f2bf(float f){
  u32 u = __float_as_uint(f);
  return (u + 0x7FFFu + ((u >> 16) & 1u)) >> 16;
}
__device__ __forceinline__ u32 pack2bf(float lo, float hi){
  return f2bf(lo) | (f2bf(hi) << 16);
}
__device__ __forceinline__ float bfu2f(u32 us){ return __uint_as_float(us << 16); }
__device__ __forceinline__ float lrelu(float x){ return x > 0.f ? x : 0.01f * x; }

// ---------- K0: weight [512][256] f32 -> wT [256][512] bf16 ----------
__global__ void k0_wt(const float* __restrict__ w, u16* __restrict__ wT){
  int u = blockIdx.x * 256 + threadIdx.x;
  int k = u >> 8, n = u & 255;
  wT[(size_t)n * 512 + k] = (u16)f2bf(w[(size_t)k * 256 + n]);
}

// ---------- K1: out = x@W -> outF (MFMA-frag layout) + v0/v1 + p(bf16) ----------
// outF element (k16, n, h, e) = out[i][n] with i = k16*16 + h*8 + e
// p computed with shift C=0 (softmax shift-invariant; w <= ~6 sigma, exp safe).
__global__ __launch_bounds__(512, 2) void k1_gemm(const float* __restrict__ x,
    const u16* __restrict__ wT, const float* __restrict__ av, u16* __restrict__ outF,
    float* __restrict__ v0, float* __restrict__ v1, u16* __restrict__ pbf){
  __shared__ float tb[8][32][36];
  __shared__ float afl[512];
  __shared__ float sred[2][32][17];
  __shared__ float srw[2][32];
  const int i0 = blockIdx.x * 32;
  const int tid = threadIdx.x;
  const int lane = tid & 63, wv = tid >> 6;
  const int r = lane & 31, h = lane >> 5;
  const float* xp = x + (size_t)(i0 + r) * 512 + h * 8;
  const u16*   bp = wT + (size_t)(wv * 32 + r) * 512 + h * 8;
  f32x16 acc = {};
  for (int s = 0; s < 32; ++s){
    f32x4 a0 = *(const f32x4*)xp;
    f32x4 a1 = *(const f32x4*)(xp + 4);
    i32x4 pk = { (int)pack2bf(a0[0], a0[1]), (int)pack2bf(a0[2], a0[3]),
                 (int)pack2bf(a1[0], a1[1]), (int)pack2bf(a1[2], a1[3]) };
    bf16x8 af = __builtin_bit_cast(bf16x8, pk);
    bf16x8 bf = *(const bf16x8*)bp;
    acc = __builtin_amdgcn_mfma_f32_32x32x16_bf16(af, bf, acc, 0, 0, 0);
    xp += 16; bp += 16;
  }
  #pragma unroll
  for (int re = 0; re < 16; ++re){
    int rr = (re & 3) + 8 * (re >> 2) + 4 * h;
    tb[wv][r][rr] = acc[re];
  }
  afl[tid] = av[tid];
  __syncthreads();
  // outF write (frag layout)
  {
    const int n2 = lane >> 1, ic = (lane & 1) * 16;
    const float* tp = &tb[wv][n2][ic];
    i32x4 w0 = { (int)pack2bf(tp[0],tp[1]),   (int)pack2bf(tp[2],tp[3]),
                 (int)pack2bf(tp[4],tp[5]),   (int)pack2bf(tp[6],tp[7]) };
    i32x4 w1 = { (int)pack2bf(tp[8],tp[9]),   (int)pack2bf(tp[10],tp[11]),
                 (int)pack2bf(tp[12],tp[13]), (int)pack2bf(tp[14],tp[15]) };
    const int n = wv * 32 + n2;
    const int k16 = (i0 + ic) >> 4;
    u16* op = outF + ((size_t)k16 * 256 + n) * 16;
    *(i32x4*)op = w0;
    *((i32x4*)op + 1) = w1;
  }
  // s-dots from f32 acc
  const int row = tid & 31, g = tid >> 5;
  const int w8 = g >> 1, fh = (g & 1) * 16;
  float a1c = 0.f, a2c = 0.f;
  #pragma unroll
  for (int f = 0; f < 16; ++f){
    float tv = tb[w8][fh + f][row];
    a1c = fmaf(tv, afl[w8 * 32 + fh + f], a1c);
    a2c = fmaf(tv, afl[256 + w8 * 32 + fh + f], a2c);
  }
  sred[0][row][g] = a1c; sred[1][row][g] = a2c;
  __syncthreads();
  if (tid < 64){
    int which = tid >> 5, r2 = tid & 31;
    float s = 0.f;
    #pragma unroll
    for (int g2 = 0; g2 < 16; ++g2) s += sred[which][r2][g2];
    srw[which][r2] = s;
  }
  __syncthreads();
  if (tid < 16){
    int k = (i0 >> 1) + tid;
    float sa  = srw[0][2*tid],   sb  = srw[1][2*tid];
    float sa1 = srw[0][2*tid+1], sb1 = srw[1][2*tid+1];
    v0[k] = lrelu(sa + sb);
    v1[k] = lrelu(sa1 + sb1);
    float w = lrelu(sa + sb1);
    pbf[k] = (u16)f2bf(__expf(w));
  }
}

// ---------- K3: binary GEMM, 64-row tiles, split-K=4, p folded into A-pack ----------
// grid 512 (2/CU): xcd<4 -> top rows, chunk c=xcd; xcd>=4 -> bottom, c=xcd-4.
// Block: 64 rows x 256 feats x K-chunk 2048 (32 phases of 64).
// Phase: B_ISS(s+1) [4 loads]; ADJ(s+2) [2 loads, alt regs]; MFMA(s) [8]; PACKW(s+1); bar.
// A-pack: w = (adj-mask) & p_bf16pair  -> bottom gets p*1hot, top gets 1.0/0.
__global__ __launch_bounds__(512, 2) void k3_main(const int* __restrict__ adj,
    const u16* __restrict__ outF, const u16* __restrict__ pbf,
    float* __restrict__ P, float* __restrict__ pd){
  __shared__ u16 Ab[2][4096];     // [buf][cc=ks*2+h (8)][row^cc (64)][8] bf16
  __shared__ u32 pl32[1024];      // p bf16-pairs for this chunk (2048 values)
  __shared__ float dred[64][9];
  const int bid = blockIdx.x;
  const int xcd = bid & 7, slot = bid >> 3;
  const bool top = xcd < 4;
  const int c = top ? xcd : xcd - 4;
  const int gt = (top ? 0 : 64) + slot;       // global tile 0..127
  const int i0 = gt * 64;
  const int kbase = c * 2048;
  const int pb = gt * 4 + c;
  const int tid = threadIdx.x, lane = tid & 63, wv = tid >> 6;
  const int r = lane & 31, h = lane >> 5, fb = wv * 32;
  const int srow = tid >> 3, sc = tid & 7;
  const int h8 = h * 8;
  const int* aq0 = adj + (size_t)(i0 + srow) * 8192 + kbase + sc * 8;
  const u16* bq0 = outF + ((size_t)(kbase >> 4) * 256 + fb + r) * 16 + h8;
  u16* const wp0 = &Ab[0][0] + sc * 512 + ((srow ^ sc) * 8);
  const u32* const pq0 = pl32 + sc * 4;

  // stage p-pairs into LDS (chunk slice: bottom j in [kbase,kbase+2048) -> p[(j)&4095])
  if (top){
    pl32[tid] = 0x3F803F80u; pl32[tid + 512] = 0x3F803F80u;
  } else {
    const u32* ps = (const u32*)pbf + (c & 1) * 1024;
    pl32[tid] = ps[tid]; pl32[tid + 512] = ps[tid + 512];
  }
  __syncthreads();

  i32x4 aA0, aA1, aB0, aB1;
  bf16x8 BA[4], BB[4];
  f32x16 acc0 = {}, acc1 = {};
  float d = 0.f;

#define ADJ_A(S_) { const int* ap_ = aq0 + (S_) * 64; \
  aA0 = __builtin_nontemporal_load((const i32x4*)ap_); \
  aA1 = __builtin_nontemporal_load((const i32x4*)(ap_ + 4)); \
  asm volatile("" ::: "memory"); }
#define ADJ_B(S_) { const int* ap_ = aq0 + (S_) * 64; \
  aB0 = __builtin_nontemporal_load((const i32x4*)ap_); \
  aB1 = __builtin_nontemporal_load((const i32x4*)(ap_ + 4)); \
  asm volatile("" ::: "memory"); }

#define B_ISS(B_,S_) { const u16* bb_ = bq0 + (size_t)(S_) * 16384; \
  _Pragma("unroll") for (int ks = 0; ks < 4; ++ks) \
    B_[ks] = *(const bf16x8*)(bb_ + ks * 4096); \
  asm volatile("" ::: "memory"); }

#define MFMA8(B_,BUF_) { const u16* rb_ = &Ab[BUF_][0]; \
  __builtin_amdgcn_s_setprio(1); \
  _Pragma("unroll") for (int ks = 0; ks < 4; ++ks){ \
    const int cc_ = ks * 2 + h; \
    bf16x8 a0_ = *(const bf16x8*)(rb_ + cc_ * 512 + ((r ^ cc_) * 8)); \
    bf16x8 a1_ = *(const bf16x8*)(rb_ + cc_ * 512 + (((32 + r) ^ cc_) * 8)); \
    acc0 = __builtin_amdgcn_mfma_f32_32x32x16_bf16(a0_, B_[ks], acc0, 0, 0, 0); \
    acc1 = __builtin_amdgcn_mfma_f32_32x32x16_bf16(a1_, B_[ks], acc1, 0, 0, 0); } \
  __builtin_amdgcn_s_setprio(0); }

#define PACKW(A0_,A1_,BUF_,S_) { \
  i32x4 pv_ = *(const i32x4*)(pq0 + (S_) * 32); \
  u32 w0_ = ((((u32)(-A0_[0])) & 0xFFFFu) | (((u32)(-A0_[1])) << 16)) & (u32)pv_[0]; \
  u32 w1_ = ((((u32)(-A0_[2])) & 0xFFFFu) | (((u32)(-A0_[3])) << 16)) & (u32)pv_[1]; \
  u32 w2_ = ((((u32)(-A1_[0])) & 0xFFFFu) | (((u32)(-A1_[1])) << 16)) & (u32)pv_[2]; \
  u32 w3_ = ((((u32)(-A1_[2])) & 0xFFFFu) | (((u32)(-A1_[3])) << 16)) & (u32)pv_[3]; \
  d += __uint_as_float(w0_ << 16) + __uint_as_float(w0_ & 0xFFFF0000u); \
  d += __uint_as_float(w1_ << 16) + __uint_as_float(w1_ & 0xFFFF0000u); \
  d += __uint_as_float(w2_ << 16) + __uint_as_float(w2_ & 0xFFFF0000u); \
  d += __uint_as_float(w3_ << 16) + __uint_as_float(w3_ & 0xFFFF0000u); \
  i32x4 wv_ = { (int)w0_, (int)w1_, (int)w2_, (int)w3_ }; \
  *(i32x4*)(wp0 + (BUF_) * 4096) = wv_; }

#define KBAR() { asm volatile("s_waitcnt lgkmcnt(0)" ::: "memory"); \
  __builtin_amdgcn_s_barrier(); asm volatile("" ::: "memory"); }

  // prologue: adj(0)->A (consumed now), B(0)->BA, adj(1)->B
  ADJ_A(0);
  B_ISS(BA, 0);
  ADJ_B(1);
  PACKW(aA0, aA1, 0, 0);
  KBAR();
  #pragma unroll 1
  for (int s = 0; s < 28; s += 2){
    B_ISS(BB, s + 1);  ADJ_A(s + 2);  MFMA8(BA, 0);  PACKW(aB0, aB1, 1, s + 1);  KBAR();
    B_ISS(BA, s + 2);  ADJ_B(s + 3);  MFMA8(BB, 1);  PACKW(aA0, aA1, 0, s + 2);  KBAR();
  }
  // tail: phases 28..31
  B_ISS(BB, 29);  ADJ_A(30);  MFMA8(BA, 0);  PACKW(aB0, aB1, 1, 29);  KBAR();
  B_ISS(BA, 30);  ADJ_B(31);  MFMA8(BB, 1);  PACKW(aA0, aA1, 0, 30);  KBAR();
  B_ISS(BB, 31);              MFMA8(BA, 0);  PACKW(aB0, aB1, 1, 31);  KBAR();
  MFMA8(BB, 1);

#undef ADJ_A
#undef ADJ_B
#undef B_ISS
#undef MFMA8
#undef PACKW
#undef KBAR

  // ---- epilogue: denominator reduce + partial store ----
  dred[srow][sc] = d;
  __syncthreads();
  if (tid < 64){
    float s = 0.f;
    #pragma unroll
    for (int q = 0; q < 8; ++q) s += dred[tid][q];
    pd[(size_t)pb * 64 + tid] = s;
  }
  float* Pb = P + (size_t)pb * 16384 + fb + r;
  #pragma unroll
  for (int e = 0; e < 16; ++e){
    int rr = (e & 3) + 8 * (e >> 2) + 4 * h;
    __builtin_nontemporal_store(acc0[e], Pb + (size_t)rr * 256);
    __builtin_nontemporal_store(acc1[e], Pb + (size_t)(rr + 32) * 256);
  }
}

// ---------- K4: combine 4 K-split partials + softmax coeffs + sigmoid ----------
__global__ void k4_final(const float* __restrict__ P, const float* __restrict__ pd,
    const float* __restrict__ v0, const float* __restrict__ v1, float* __restrict__ out){
  const int i = blockIdx.x, n = threadIdx.x;
  const int tile = i >> 6, rloc = i & 63;
  const size_t base = ((size_t)tile * 4 * 64 + rloc) * 256 + n;
  float P0 = __builtin_nontemporal_load(P + base);
  float P1 = __builtin_nontemporal_load(P + base + 16384);
  float P2 = __builtin_nontemporal_load(P + base + 32768);
  float P3 = __builtin_nontemporal_load(P + base + 49152);
  const float* pdp = pd + (size_t)tile * 256 + rloc;
  float d0 = pdp[0], d1 = pdp[64], d2 = pdp[128], d3 = pdp[192];
  float val;
  if (i < 4096){
    float va = v0[i], vb = v1[i];
    float m = fmaxf(va, vb);
    float e0 = __expf(va - m), e1 = __expf(vb - m);
    val = (e0 * (P0 + P1) + e1 * (P2 + P3)) / (e0 * (d0 + d1) + e1 * (d2 + d3));
  } else {
    val = (P0 + P1 + P2 + P3) / (d0 + d1 + d2 + d3);
  }
  out[(size_t)i * 256 + n] = 1.0f / (1.0f + __expf(-val));
}

extern "C" void kernel_launch(void* const* d_in, const int* in_sizes, int n_in,
                              void* d_out, int out_size, void* d_ws, size_t ws_size,
                              hipStream_t stream)
{
  const float* x      = (const float*)d_in[0];
  const float* weight = (const float*)d_in[1];
  const float* av     = (const float*)d_in[2];
  const int*   adj    = (const int*)d_in[3];
  float* out = (float*)d_out;
  char* ws = (char*)d_ws;
  float* P     = (float*)(ws + 0);             // 33,554,432 B
  float* pd    = (float*)(ws + 33554432);      //    131,072 B
  u16*   outF  = (u16*)  (ws + 33685504);      //  4,194,304 B
  u16*   wT    = (u16*)  (ws + 37879808);      //    262,144 B
  u16*   pbf   = (u16*)  (ws + 38141952);      //      8,192 B
  float* v0    = (float*)(ws + 38150144);      //     16,384 B
  float* v1    = (float*)(ws + 38166528);      //     16,384 B

  k0_wt    <<<512, 256, 0, stream>>>(weight, wT);
  k1_gemm  <<<256, 512, 0, stream>>>(x, wT, av, outF, v0, v1, pbf);
  k3_main  <<<512, 512, 0, stream>>>(adj, outF, pbf, P, pd);
  k4_final <<<8192, 256, 0, stream>>>(P, pd, v0, v1, out);
}